// Round 1
// baseline (83.422 us; speedup 1.0000x reference)
//
#include <hip/hip_runtime.h>
#include <hip/hip_bf16.h>

// GraphProp: layered DAG topological propagation.
// N=50000 nodes, L=16 levels, PER=3125 nodes/level, DEG=16 in-edges, D=64 feat dim.
// Edges are sorted by dst; node v (v >= PER) owns edges [(v-PER)*16, (v-PER)*16+16).
// feat[v] = max_k(feat[src_k] + intra_delay[src_k]) + delay[v], levels processed in order.

#define NN    50000
#define LVL   16
#define PER   3125
#define DEG   16
#define DF    64

// One wave (64 lanes) per node; lane = feature index d. 4 nodes per 256-thread block.
__global__ void __launch_bounds__(256) prop_level(
    float* __restrict__ feat,          // d_out, in-place (reads earlier levels only)
    const float* __restrict__ intra,   // intra_delay
    const float* __restrict__ delay,   // delay
    const int*  __restrict__ src,      // edge src indices
    int level_start)                   // first node of this level
{
    const int idx = blockIdx.x * 4 + (threadIdx.x >> 6);   // node within level
    if (idx >= PER) return;
    const int v = level_start + idx;
    const int d = threadIdx.x & 63;
    const long ebase = (long)(v - PER) * DEG;

    float m = -INFINITY;
#pragma unroll
    for (int k = 0; k < DEG; ++k) {
        const int s = src[ebase + k];
        const float val = feat[(long)s * DF + d] + intra[(long)s * DF + d];
        m = fmaxf(m, val);
    }
    feat[(long)v * DF + d] = m + delay[(long)v * DF + d];
}

extern "C" void kernel_launch(void* const* d_in, const int* in_sizes, int n_in,
                              void* d_out, int out_size, void* d_ws, size_t ws_size,
                              hipStream_t stream) {
    const float* feat  = (const float*)d_in[0];
    const float* delay = (const float*)d_in[1];
    const float* intra = (const float*)d_in[2];
    const int*   src   = (const int*)d_in[3];
    // d_in[4] = dst (implicit: sorted, contiguous), d_in[5] = node_levels (implicit: v/PER)
    float* out = (float*)d_out;

    // Level 0 (and initial values of all nodes): copy feat into d_out.
    hipMemcpyAsync(out, feat, (size_t)NN * DF * sizeof(float),
                   hipMemcpyDeviceToDevice, stream);

    const int blocks = (PER + 3) / 4;   // 4 nodes per block
    for (int l = 1; l < LVL; ++l) {
        prop_level<<<blocks, 256, 0, stream>>>(out, intra, delay, src, l * PER);
    }
}